// Round 2
// baseline (1985.383 us; speedup 1.0000x reference)
//
#include <hip/hip_runtime.h>
#include <math.h>

#define N_NODES 10000
#define N_EDGES 160000
// C0=64 C1=32 RBF=64 HID=128 NW=224 HEADS=8 ALPHA_DIM=32 HEAD_S=16 HEAD_V=8
#define SQRT3 1.7320508075688772f
#define INV_SQRT2 0.7071067811865476f

__device__ __forceinline__ float sigmoidf_(float x) { return 1.f / (1.f + expf(-x)); }

// ---------------- Kernel 1: node transforms ----------------
// ssrc = x_s @ Ws_src, sdst = x_s @ Ws_dst   (N,64)
// vsrc[n,d,i] = sum_c x_v[n,c,i] * Wv_src[c,d]   (N,32,3) ; same for vdst
__global__ __launch_bounds__(256) void node_xform(
    const float* __restrict__ xs, const float* __restrict__ xv,
    const float* __restrict__ Wss, const float* __restrict__ Wsd,
    const float* __restrict__ Wvs, const float* __restrict__ Wvd,
    float* __restrict__ ssrc, float* __restrict__ sdst,
    float* __restrict__ vsrc, float* __restrict__ vdst)
{
    const int nth = gridDim.x * blockDim.x;
    const int tid0 = blockIdx.x * blockDim.x + threadIdx.x;

    for (int t = tid0; t < N_NODES * 128; t += nth) {
        int n = t >> 7, r = t & 127, which = r >> 6, d = r & 63;
        const float* W = which ? Wsd : Wss;
        const float* x = xs + n * 64;
        float acc = 0.f;
        #pragma unroll 8
        for (int c = 0; c < 64; ++c) acc = fmaf(x[c], W[c * 64 + d], acc);
        (which ? sdst : ssrc)[n * 64 + d] = acc;
    }
    for (int t = tid0; t < N_NODES * 192; t += nth) {
        int n = t / 192, r = t % 192, which = r / 96, j = r % 96;
        int d = j / 3, i = j - 3 * d;
        const float* W = which ? Wvd : Wvs;
        const float* x = xv + n * 96;
        float acc = 0.f;
        #pragma unroll 8
        for (int c = 0; c < 32; ++c) acc = fmaf(x[c * 3 + i], W[c * 32 + d], acc);
        (which ? vdst : vsrc)[n * 96 + j] = acc;
    }
}

// ---------------- Kernel 2: fused per-edge pipeline ----------------
// 8 edges per 256-thread block. Accumulates unnormalized sums via atomics:
//   denom[n,h] += exp(logit);  aggs[n,h*16+k] += ex*val_s;  aggv[n,d*3+i] += ex*val_v
__global__ __launch_bounds__(256) void edge_kernel(
    const float* __restrict__ edge_scalars, const float* __restrict__ edge_vec,
    const int* __restrict__ edge_src, const int* __restrict__ edge_dst,
    const float* __restrict__ ssrc, const float* __restrict__ sdst,
    const float* __restrict__ vsrc, const float* __restrict__ vdst,
    const float* __restrict__ rad_W1, const float* __restrict__ rad_b1,
    const float* __restrict__ rad_W2, const float* __restrict__ rad_b2,
    const float* __restrict__ lin_s_W, const float* __restrict__ lin_s_b,
    const float* __restrict__ lin_v_W, const float* __restrict__ alpha_dot,
    float* __restrict__ denom, float* __restrict__ aggs, float* __restrict__ aggv)
{
    __shared__ float es[8][64];     // edge_scalars tile
    __shared__ float msb[8][64];    // ms
    __shared__ float mvb[8][96];    // mv (c,i) flat
    __shared__ float unitb[8][3];
    __shared__ float hbuf[8][128];  // silu(es@W1+b1)
    __shared__ float wbuf[8][224];  // radial weights
    __shared__ float tps[8][96];
    __shared__ float tpv[8][384];   // (c,i) flat, c<128
    __shared__ float fsb[8][384];   // f_s
    __shared__ float vvb[8][192];   // val_v (d,i) flat, d<64
    __shared__ float exb[8][8];
    __shared__ int srcb[8], dstb[8];

    const int tid = threadIdx.x;
    const int e0 = blockIdx.x * 8;

    if (tid < 8) {
        srcb[tid] = edge_src[e0 + tid];
        dstb[tid] = edge_dst[e0 + tid];
        float x = edge_vec[(e0 + tid) * 3 + 0];
        float y = edge_vec[(e0 + tid) * 3 + 1];
        float z = edge_vec[(e0 + tid) * 3 + 2];
        float rn = 1.f / (sqrtf(x * x + y * y + z * z) + 1e-9f);
        unitb[tid][0] = x * rn; unitb[tid][1] = y * rn; unitb[tid][2] = z * rn;
    }
    #pragma unroll
    for (int k = 0; k < 2; ++k) {
        int idx = tid + k * 256;
        ((float*)es)[idx] = edge_scalars[e0 * 64 + idx];
    }
    __syncthreads();   // srcb/dstb, es, unit ready

    // gathers (independent of phase h below; same barrier region)
    #pragma unroll
    for (int k = 0; k < 2; ++k) {
        int idx = tid + k * 256;
        int e = idx >> 6, c = idx & 63;
        msb[e][c] = ssrc[srcb[e] * 64 + c] + sdst[dstb[e] * 64 + c];
    }
    #pragma unroll
    for (int k = 0; k < 3; ++k) {
        int idx = tid + k * 256;
        int e = idx / 96, j = idx % 96;
        mvb[e][j] = vsrc[srcb[e] * 96 + j] + vdst[dstb[e] * 96 + j];
    }

    // phase h: (8e x 128) = silu(es @ rad_W1 + b1), 32 threads/edge, 4 cols each
    {
        int e = tid >> 5, jb = tid & 31;
        float a0 = 0, a1 = 0, a2 = 0, a3 = 0;
        for (int c = 0; c < 64; ++c) {
            float s = es[e][c];
            const float4 w4 = *reinterpret_cast<const float4*>(&rad_W1[c * 128 + jb * 4]);
            a0 = fmaf(s, w4.x, a0); a1 = fmaf(s, w4.y, a1);
            a2 = fmaf(s, w4.z, a2); a3 = fmaf(s, w4.w, a3);
        }
        const float4 b4 = *reinterpret_cast<const float4*>(&rad_b1[jb * 4]);
        a0 += b4.x; a1 += b4.y; a2 += b4.z; a3 += b4.w;
        hbuf[e][jb * 4 + 0] = a0 * sigmoidf_(a0);
        hbuf[e][jb * 4 + 1] = a1 * sigmoidf_(a1);
        hbuf[e][jb * 4 + 2] = a2 * sigmoidf_(a2);
        hbuf[e][jb * 4 + 3] = a3 * sigmoidf_(a3);
    }
    __syncthreads();

    // phase w: (8e x 224) = h @ rad_W2 + b2, 32 threads/edge, 7 cols each
    {
        int e = tid >> 5, jb = tid & 31;
        float acc[7] = {0, 0, 0, 0, 0, 0, 0};
        for (int c = 0; c < 128; ++c) {
            float hv = hbuf[e][c];
            const float* wr = rad_W2 + c * 224 + jb;
            #pragma unroll
            for (int k = 0; k < 7; ++k) acc[k] = fmaf(hv, wr[k * 32], acc[k]);
        }
        #pragma unroll
        for (int k = 0; k < 7; ++k) wbuf[e][jb + k * 32] = acc[k] + rad_b2[jb + k * 32];
    }
    __syncthreads();

    // phase tp_s: wA*ms | wD*(mv.unit)     (w layout: A[0:64] B[64:128] C[128:160] D[160:192] E[192:224])
    #pragma unroll
    for (int k = 0; k < 3; ++k) {
        int idx = tid + k * 256;
        int e = idx / 96, j = idx % 96;
        if (j < 64) {
            tps[e][j] = wbuf[e][j] * msb[e][j];
        } else {
            int d = j - 64;
            float dot = mvb[e][d * 3 + 0] * unitb[e][0] + mvb[e][d * 3 + 1] * unitb[e][1]
                      + mvb[e][d * 3 + 2] * unitb[e][2];
            tps[e][j] = wbuf[e][160 + d] * dot;
        }
    }
    // phase tp_v: [wB*ms*sh1 ; wC*mv ; wE*cross(mv,sh1)/sqrt2]
    #pragma unroll
    for (int k = 0; k < 12; ++k) {
        int idx = tid + k * 256;
        int e = idx / 384, j = idx % 384;
        int c = j / 3, i = j - 3 * c;
        float v;
        if (c < 64) {
            v = wbuf[e][64 + c] * msb[e][c] * SQRT3 * unitb[e][i];
        } else if (c < 96) {
            int d = c - 64;
            v = wbuf[e][128 + d] * mvb[e][d * 3 + i];
        } else {
            int d = c - 96;
            float a0v = mvb[e][d * 3 + 0], a1v = mvb[e][d * 3 + 1], a2v = mvb[e][d * 3 + 2];
            float cr;
            if (i == 0)      cr = a1v * unitb[e][2] - a2v * unitb[e][1];
            else if (i == 1) cr = a2v * unitb[e][0] - a0v * unitb[e][2];
            else             cr = a0v * unitb[e][1] - a1v * unitb[e][0];
            v = wbuf[e][192 + d] * cr * (SQRT3 * INV_SQRT2);
        }
        tpv[e][j] = v;
    }
    __syncthreads();

    // phase f_s: (8e x 384) = tp_s @ lin_s_W + b, 32 threads/edge, 12 cols each
    {
        int e = tid >> 5, jb = tid & 31;
        float acc[12];
        #pragma unroll
        for (int k = 0; k < 12; ++k) acc[k] = lin_s_b[jb + k * 32];
        for (int c = 0; c < 96; ++c) {
            float t = tps[e][c];
            const float* wr = lin_s_W + c * 384 + jb;
            #pragma unroll
            for (int k = 0; k < 12; ++k) acc[k] = fmaf(t, wr[k * 32], acc[k]);
        }
        #pragma unroll
        for (int k = 0; k < 12; ++k) fsb[e][jb + k * 32] = acc[k];
    }
    // phase val_v: (8e x 192): vv[d,i] = sum_c tpv[c,i]*lin_v_W[c,d]
    {
        int e = tid >> 5, jb = tid & 31;
        int jj[6], dd[6], ii[6];
        #pragma unroll
        for (int k = 0; k < 6; ++k) { jj[k] = jb + k * 32; dd[k] = jj[k] / 3; ii[k] = jj[k] - 3 * dd[k]; }
        float acc[6] = {0, 0, 0, 0, 0, 0};
        for (int c = 0; c < 128; ++c) {
            float tv0 = tpv[e][c * 3 + 0], tv1 = tpv[e][c * 3 + 1], tv2 = tpv[e][c * 3 + 2];
            const float* wr = lin_v_W + c * 64;
            #pragma unroll
            for (int k = 0; k < 6; ++k) {
                float tv = (ii[k] == 0) ? tv0 : ((ii[k] == 1) ? tv1 : tv2);
                acc[k] = fmaf(tv, wr[dd[k]], acc[k]);
            }
        }
        #pragma unroll
        for (int k = 0; k < 6; ++k) vvb[e][jj[k]] = acc[k];
    }
    __syncthreads();

    // logits -> ex (no max subtraction: mathematically identical after normalize)
    if (tid < 64) {
        int e = tid >> 3, h = tid & 7;
        float acc = 0.f;
        #pragma unroll 8
        for (int d2 = 0; d2 < 32; ++d2) {
            float x = fsb[e][h * 48 + d2];
            float sg = 1.f / (1.f + expf(-x));
            float slr = 0.6f * x + 0.4f * x * (2.f * sg - 1.f);
            acc = fmaf(slr, alpha_dot[h * 32 + d2], acc);
        }
        exb[e][h] = expf(acc);
    }
    __syncthreads();

    // scatter-accumulate
    if (tid < 64) {
        int e = tid >> 3, h = tid & 7;
        atomicAdd(&denom[dstb[e] * 8 + h], exb[e][h]);
    }
    #pragma unroll
    for (int k = 0; k < 4; ++k) {
        int idx = tid + k * 256;
        int e = idx >> 7, r = idx & 127, h = r >> 4, kk = r & 15;
        atomicAdd(&aggs[dstb[e] * 128 + r], exb[e][h] * fsb[e][h * 48 + 32 + kk]);
    }
    #pragma unroll
    for (int k = 0; k < 6; ++k) {
        int idx = tid + k * 256;
        int e = idx / 192, j = idx % 192;
        int d = j / 3, h = d >> 3;
        atomicAdd(&aggv[dstb[e] * 192 + j], exb[e][h] * vvb[e][j]);
    }
}

// ---------------- Kernel 3: normalize + output projections ----------------
__global__ __launch_bounds__(64) void finalize(
    const float* __restrict__ aggs, const float* __restrict__ aggv,
    const float* __restrict__ denom,
    const float* __restrict__ psW, const float* __restrict__ psb,
    const float* __restrict__ pvW,
    float* __restrict__ outs, float* __restrict__ outv)
{
    const int n = blockIdx.x;
    const int tid = threadIdx.x;
    __shared__ float rs[128], rv[192], dn[8];
    if (tid < 8) dn[tid] = 1.f / (denom[n * 8 + tid] + 1e-9f);
    __syncthreads();
    #pragma unroll
    for (int k = tid; k < 128; k += 64) rs[k] = aggs[n * 128 + k] * dn[k >> 4];
    #pragma unroll
    for (int k = tid; k < 192; k += 64) { int d = k / 3; rv[k] = aggv[n * 192 + k] * dn[d >> 3]; }
    __syncthreads();

    // out_s: 64 outputs, K=128
    {
        float acc = psb[tid];
        #pragma unroll 8
        for (int c = 0; c < 128; ++c) acc = fmaf(rs[c], psW[c * 64 + tid], acc);
        outs[n * 64 + tid] = acc;
    }
    // out_v: 96 outputs, K=64
    for (int j = tid; j < 96; j += 64) {
        int d = j / 3, i = j - 3 * d;
        float acc = 0.f;
        #pragma unroll 8
        for (int c = 0; c < 64; ++c) acc = fmaf(rv[c * 3 + i], pvW[c * 32 + d], acc);
        outv[n * 96 + j] = acc;
    }
}

extern "C" void kernel_launch(void* const* d_in, const int* in_sizes, int n_in,
                              void* d_out, int out_size, void* d_ws, size_t ws_size,
                              hipStream_t stream) {
    const float* x_s         = (const float*)d_in[0];
    const float* x_v         = (const float*)d_in[1];
    const float* edge_vec    = (const float*)d_in[2];
    const float* edge_scal   = (const float*)d_in[3];
    const int*   edge_src    = (const int*)d_in[4];
    const int*   edge_dst    = (const int*)d_in[5];
    const float* Ws_src      = (const float*)d_in[6];
    const float* Ws_dst      = (const float*)d_in[7];
    const float* Wv_src      = (const float*)d_in[8];
    const float* Wv_dst      = (const float*)d_in[9];
    const float* rad_W1      = (const float*)d_in[10];
    const float* rad_b1      = (const float*)d_in[11];
    const float* rad_W2      = (const float*)d_in[12];
    const float* rad_b2      = (const float*)d_in[13];
    const float* lin_s_W     = (const float*)d_in[14];
    const float* lin_s_b     = (const float*)d_in[15];
    const float* lin_v_W     = (const float*)d_in[16];
    const float* alpha_dot   = (const float*)d_in[17];
    const float* proj_s_W    = (const float*)d_in[18];
    const float* proj_s_b    = (const float*)d_in[19];
    const float* proj_v_W    = (const float*)d_in[20];

    float* ws   = (float*)d_ws;
    float* ssrc = ws;                    // N*64
    float* sdst = ssrc + 640000;         // N*64
    float* vsrc = sdst + 640000;         // N*96
    float* vdst = vsrc + 960000;         // N*96
    float* denom = vdst + 960000;        // N*8
    float* aggs  = denom + 80000;        // N*128
    float* aggv  = aggs + 1280000;       // N*192

    // zero only the accumulator regions (contiguous)
    hipMemsetAsync(denom, 0, (size_t)(80000 + 1280000 + 1920000) * sizeof(float), stream);

    node_xform<<<2048, 256, 0, stream>>>(x_s, x_v, Ws_src, Ws_dst, Wv_src, Wv_dst,
                                         ssrc, sdst, vsrc, vdst);
    edge_kernel<<<N_EDGES / 8, 256, 0, stream>>>(edge_scal, edge_vec, edge_src, edge_dst,
        ssrc, sdst, vsrc, vdst, rad_W1, rad_b1, rad_W2, rad_b2,
        lin_s_W, lin_s_b, lin_v_W, alpha_dot, denom, aggs, aggv);

    float* outs = (float*)d_out;
    float* outv = outs + 640000;
    finalize<<<N_NODES, 64, 0, stream>>>(aggs, aggv, denom, proj_s_W, proj_s_b, proj_v_W,
                                         outs, outv);
}

// Round 4
// 649.439 us; speedup vs baseline: 3.0571x; 3.0571x over previous
//
#include <hip/hip_runtime.h>
#include <math.h>

#define N_NODES 10000
#define N_EDGES 160000
// C0=64 C1=32 RBF=64 HID=128 NW=224 HEADS=8 ALPHA_DIM=32 HEAD_S=16 HEAD_V=8
#define SQRT3 1.7320508075688772f
#define INV_SQRT2 0.7071067811865476f

typedef __attribute__((ext_vector_type(8))) short bf16x8;
typedef __attribute__((ext_vector_type(4))) float f32x4;

__device__ __forceinline__ float b2f(unsigned short u) {
    union { unsigned u; float f; } x; x.u = ((unsigned)u) << 16; return x.f;
}
__device__ __forceinline__ unsigned short f2b(float f) {
    union { float f; unsigned u; } x; x.f = f;
    unsigned r = x.u + 0x7FFFu + ((x.u >> 16) & 1u);   // RNE
    return (unsigned short)(r >> 16);
}
__device__ __forceinline__ float sigmoidf_(float x) { return 1.f / (1.f + expf(-x)); }

// ---------------- Kernel 0: weight prep ----------------
// Re-layout each GEMM weight W[K][N] (f32) into bf16 MFMA B-fragment order:
// F[blk = nt*KS+ks][lane][j] = bf16( W[ks*32 + (lane>>4)*8 + j][nt*16 + (lane&15)] )
// so an edge-kernel wave loads its B-fragment as one coalesced 16B read per lane.
__global__ __launch_bounds__(256) void prep_weights(
    const float* __restrict__ W1, const float* __restrict__ W2,
    const float* __restrict__ Ls, const float* __restrict__ Lv,
    unsigned short* __restrict__ F1, unsigned short* __restrict__ F2,
    unsigned short* __restrict__ F3, unsigned short* __restrict__ F4)
{
    int t = blockIdx.x * 256 + threadIdx.x;
    const float* src; unsigned short* dst; int N, KS, rel;
    if      (t < 8192)  { src = W1; dst = F1; N = 128; KS = 2; rel = t; }
    else if (t < 36864) { src = W2; dst = F2; N = 224; KS = 4; rel = t - 8192; }
    else if (t < 73728) { src = Ls; dst = F3; N = 384; KS = 3; rel = t - 36864; }
    else if (t < 81920) { src = Lv; dst = F4; N = 64;  KS = 4; rel = t - 73728; }
    else return;
    int j = rel & 7, lane = (rel >> 3) & 63, blk = rel >> 9;
    int nt = blk / KS, ks = blk - nt * KS;
    int k = ks * 32 + ((lane >> 4) << 3) + j;
    int n = nt * 16 + (lane & 15);
    dst[rel] = f2b(src[k * N + n]);
}

// ---------------- Kernel 1: node transforms (bf16 out) ----------------
__global__ __launch_bounds__(256) void node_xform(
    const float* __restrict__ xs, const float* __restrict__ xv,
    const float* __restrict__ Wss, const float* __restrict__ Wsd,
    const float* __restrict__ Wvs, const float* __restrict__ Wvd,
    unsigned short* __restrict__ ssrc, unsigned short* __restrict__ sdst,
    unsigned short* __restrict__ vsrc, unsigned short* __restrict__ vdst)
{
    const int nth = gridDim.x * blockDim.x;
    const int tid0 = blockIdx.x * blockDim.x + threadIdx.x;

    for (int t = tid0; t < N_NODES * 128; t += nth) {
        int n = t >> 7, r = t & 127, which = r >> 6, d = r & 63;
        const float* W = which ? Wsd : Wss;
        const float* x = xs + n * 64;
        float acc = 0.f;
        #pragma unroll 8
        for (int c = 0; c < 64; ++c) acc = fmaf(x[c], W[c * 64 + d], acc);
        (which ? sdst : ssrc)[n * 64 + d] = f2b(acc);
    }
    for (int t = tid0; t < N_NODES * 192; t += nth) {
        int n = t / 192, r = t % 192, which = r / 96, j = r % 96;
        int d = j / 3, i = j - 3 * d;
        const float* W = which ? Wvd : Wvs;
        const float* x = xv + n * 96;
        float acc = 0.f;
        #pragma unroll 8
        for (int c = 0; c < 32; ++c) acc = fmaf(x[c * 3 + i], W[c * 32 + d], acc);
        (which ? vdst : vsrc)[n * 96 + j] = f2b(acc);
    }
}

// ---------------- Kernel 2: fused per-edge pipeline, MFMA GEMMs ----------------
// 16 edges/block (M=16), 4 waves. GEMMs: rad1 16x128x64, rad2 16x224x128,
// lin_s 16x384x96, lin_v 48x64x128 (rows=(e,i)). A from swizzled LDS bf16,
// B from pre-fragmented global bf16. f_s stays in registers; softmax logits via
// in-wave shfl reduce; unnormalized exp-weighted atomics into denom/aggs/aggv.
__global__ __launch_bounds__(256, 4) void edge_kernel(
    const float* __restrict__ edge_scalars, const float* __restrict__ edge_vec,
    const int* __restrict__ edge_src, const int* __restrict__ edge_dst,
    const unsigned short* __restrict__ ssrc, const unsigned short* __restrict__ sdst,
    const unsigned short* __restrict__ vsrc, const unsigned short* __restrict__ vdst,
    const unsigned short* __restrict__ W1F, const unsigned short* __restrict__ W2F,
    const unsigned short* __restrict__ LsF, const unsigned short* __restrict__ LvF,
    const float* __restrict__ rad_b1, const float* __restrict__ rad_b2,
    const float* __restrict__ lin_s_b, const float* __restrict__ alpha_dot,
    float* __restrict__ denom, float* __restrict__ aggs, float* __restrict__ aggv)
{
    __shared__ unsigned short es_s[16 * 64];    // swizzled (MFMA A)
    __shared__ unsigned short ms_s[16 * 64];    // plain (elementwise)
    __shared__ unsigned short mv_s[16 * 96];    // plain
    __shared__ unsigned short h_s[16 * 128];    // swizzled (MFMA A)
    __shared__ unsigned short w_s[16 * 224];    // plain
    __shared__ unsigned short tps_s[16 * 128];  // swizzled, cols 0..95 used
    __shared__ unsigned short tpv_s[48 * 128];  // swizzled, rows=(e,i)
    __shared__ float exb_s[16 * 8];
    __shared__ int srcb[16], dstb[16];
    __shared__ float unitb[16][3];

    const int tid = threadIdx.x;
    const int e0 = blockIdx.x * 16;
    const int lane = tid & 63;
    const int wv = tid >> 6;
    const int frow = lane & 15;   // A-row / D-col within tile
    const int fgrp = lane >> 4;   // k-group / D-row group
    const int k8 = fgrp << 3;

    if (tid < 16) {
        srcb[tid] = edge_src[e0 + tid];
        dstb[tid] = edge_dst[e0 + tid];
        float x = edge_vec[(e0 + tid) * 3 + 0];
        float y = edge_vec[(e0 + tid) * 3 + 1];
        float z = edge_vec[(e0 + tid) * 3 + 2];
        float rn = 1.f / (sqrtf(x * x + y * y + z * z) + 1e-9f);
        unitb[tid][0] = x * rn; unitb[tid][1] = y * rn; unitb[tid][2] = z * rn;
    }
    #pragma unroll
    for (int k = 0; k < 4; ++k) {
        int idx = tid + k * 256, e = idx >> 6, c = idx & 63;
        es_s[e * 64 + (c ^ ((e & 7) << 3))] = f2b(edge_scalars[(size_t)(e0 + e) * 64 + c]);
    }
    __syncthreads();

    // ---- gathers (consumed after next barrier) + rad1 MFMA in same region ----
    #pragma unroll
    for (int k = 0; k < 4; ++k) {
        int idx = tid + k * 256, e = idx >> 6, c = idx & 63;
        ms_s[e * 64 + c] = f2b(b2f(ssrc[srcb[e] * 64 + c]) + b2f(sdst[dstb[e] * 64 + c]));
    }
    #pragma unroll
    for (int k = 0; k < 6; ++k) {
        int idx = tid + k * 256, e = idx / 96, j = idx - e * 96;
        mv_s[e * 96 + j] = f2b(b2f(vsrc[srcb[e] * 96 + j]) + b2f(vdst[dstb[e] * 96 + j]));
    }
    {   // rad1: h = silu(es @ W1 + b1)   M16 N128 K64; wave -> 2 col-tiles
        const int swz = (frow & 7) << 3;
        bf16x8 a0 = *reinterpret_cast<const bf16x8*>(&es_s[frow * 64 + (k8 ^ swz)]);
        bf16x8 a1 = *reinterpret_cast<const bf16x8*>(&es_s[frow * 64 + ((32 + k8) ^ swz)]);
        #pragma unroll
        for (int t = 0; t < 2; ++t) {
            int nt = wv * 2 + t;
            f32x4 acc = {0.f, 0.f, 0.f, 0.f};
            acc = __builtin_amdgcn_mfma_f32_16x16x32_bf16(a0,
                  *reinterpret_cast<const bf16x8*>(&W1F[((nt * 2 + 0) * 64 + lane) * 8]), acc, 0, 0, 0);
            acc = __builtin_amdgcn_mfma_f32_16x16x32_bf16(a1,
                  *reinterpret_cast<const bf16x8*>(&W1F[((nt * 2 + 1) * 64 + lane) * 8]), acc, 0, 0, 0);
            int col = nt * 16 + frow;
            float bias = rad_b1[col];
            #pragma unroll
            for (int r = 0; r < 4; ++r) {
                int row = fgrp * 4 + r;
                float x = acc[r] + bias;
                h_s[row * 128 + (col ^ ((row & 7) << 3))] = f2b(x * sigmoidf_(x));
            }
        }
    }
    __syncthreads();

    {   // rad2: w = h @ W2 + b2   M16 N224 K128; 14 tiles over 4 waves
        const int swz = (frow & 7) << 3;
        bf16x8 ah[4];
        #pragma unroll
        for (int ks = 0; ks < 4; ++ks)
            ah[ks] = *reinterpret_cast<const bf16x8*>(&h_s[frow * 128 + ((ks * 32 + k8) ^ swz)]);
        for (int nt = wv; nt < 14; nt += 4) {
            f32x4 acc = {0.f, 0.f, 0.f, 0.f};
            #pragma unroll
            for (int ks = 0; ks < 4; ++ks)
                acc = __builtin_amdgcn_mfma_f32_16x16x32_bf16(ah[ks],
                      *reinterpret_cast<const bf16x8*>(&W2F[((nt * 4 + ks) * 64 + lane) * 8]), acc, 0, 0, 0);
            int col = nt * 16 + frow;
            float bias = rad_b2[col];
            #pragma unroll
            for (int r = 0; r < 4; ++r) {
                int row = fgrp * 4 + r;
                w_s[row * 224 + col] = f2b(acc[r] + bias);
            }
        }
    }
    __syncthreads();

    // ---- tp assembly (elementwise f32, bf16 in/out) ----
    // w layout: A[0:64] B[64:128] C[128:160] D[160:192] E[192:224]
    #pragma unroll
    for (int k = 0; k < 4; ++k) {   // tps cols 0..63: wA*ms
        int idx = tid + k * 256, e = idx >> 6, j = idx & 63;
        float v = b2f(w_s[e * 224 + j]) * b2f(ms_s[e * 64 + j]);
        tps_s[e * 128 + (j ^ ((e & 7) << 3))] = f2b(v);
    }
    #pragma unroll
    for (int k = 0; k < 2; ++k) {   // tps cols 64..95: wD*(mv.unit)
        int idx = tid + k * 256, e = idx >> 5, d = idx & 31;
        float dot = b2f(mv_s[e * 96 + d * 3 + 0]) * unitb[e][0]
                  + b2f(mv_s[e * 96 + d * 3 + 1]) * unitb[e][1]
                  + b2f(mv_s[e * 96 + d * 3 + 2]) * unitb[e][2];
        float v = b2f(w_s[e * 224 + 160 + d]) * dot;
        int j = 64 + d;
        tps_s[e * 128 + (j ^ ((e & 7) << 3))] = f2b(v);
    }
    for (int k = 0; k < 24; ++k) {  // tpv rows=(e,i) 48 x 128
        int idx = tid + k * 256;
        int row = idx >> 7, c = idx & 127;
        int e = row / 3, i = row - e * 3;
        float v;
        if (c < 64) {
            v = b2f(w_s[e * 224 + 64 + c]) * b2f(ms_s[e * 64 + c]) * SQRT3 * unitb[e][i];
        } else if (c < 96) {
            int d = c - 64;
            v = b2f(w_s[e * 224 + 128 + d]) * b2f(mv_s[e * 96 + d * 3 + i]);
        } else {
            int d = c - 96;
            float m0 = b2f(mv_s[e * 96 + d * 3 + 0]);
            float m1 = b2f(mv_s[e * 96 + d * 3 + 1]);
            float m2 = b2f(mv_s[e * 96 + d * 3 + 2]);
            float cr = (i == 0) ? (m1 * unitb[e][2] - m2 * unitb[e][1])
                     : (i == 1) ? (m2 * unitb[e][0] - m0 * unitb[e][2])
                                : (m0 * unitb[e][1] - m1 * unitb[e][0]);
            v = b2f(w_s[e * 224 + 192 + d]) * cr * (SQRT3 * INV_SQRT2);
        }
        tpv_s[row * 128 + (c ^ ((row & 7) << 3))] = f2b(v);
    }
    __syncthreads();

    {   // lin_s: f_s = tps @ Ls + b  M16 N384 K96; wave -> 6 tiles = heads 2w,2w+1
        const int swz = (frow & 7) << 3;
        bf16x8 at[3];
        #pragma unroll
        for (int ks = 0; ks < 3; ++ks)
            at[ks] = *reinterpret_cast<const bf16x8*>(&tps_s[frow * 128 + ((ks * 32 + k8) ^ swz)]);
        f32x4 acc[6];
        #pragma unroll
        for (int t = 0; t < 6; ++t) {
            int nt = wv * 6 + t;
            f32x4 a = {0.f, 0.f, 0.f, 0.f};
            #pragma unroll
            for (int ks = 0; ks < 3; ++ks)
                a = __builtin_amdgcn_mfma_f32_16x16x32_bf16(at[ks],
                    *reinterpret_cast<const bf16x8*>(&LsF[((nt * 3 + ks) * 64 + lane) * 8]), a, 0, 0, 0);
            float bias = lin_s_b[nt * 16 + frow];
            a[0] += bias; a[1] += bias; a[2] += bias; a[3] += bias;
            acc[t] = a;
        }
        #pragma unroll
        for (int hh = 0; hh < 2; ++hh) {
            int h = wv * 2 + hh, t0 = hh * 3;
            float ad0 = alpha_dot[h * 32 + frow];
            float ad1 = alpha_dot[h * 32 + 16 + frow];
            float part[4];
            #pragma unroll
            for (int r = 0; r < 4; ++r) {
                float x0 = acc[t0][r], x1 = acc[t0 + 1][r];
                float s0 = 0.6f * x0 + 0.4f * x0 * (2.f * sigmoidf_(x0) - 1.f);
                float s1 = 0.6f * x1 + 0.4f * x1 * (2.f * sigmoidf_(x1) - 1.f);
                part[r] = s0 * ad0 + s1 * ad1;
            }
            #pragma unroll
            for (int off = 1; off < 16; off <<= 1) {
                #pragma unroll
                for (int r = 0; r < 4; ++r) part[r] += __shfl_xor(part[r], off, 64);
            }
            #pragma unroll
            for (int r = 0; r < 4; ++r) {
                float ex = expf(part[r]);   // no max-subtraction: normalized later
                int e = fgrp * 4 + r;
                int dst = dstb[e];
                if (frow == 0) { atomicAdd(&denom[dst * 8 + h], ex); exb_s[e * 8 + h] = ex; }
                atomicAdd(&aggs[(size_t)dst * 128 + h * 16 + frow], ex * acc[t0 + 2][r]);
            }
        }
    }
    __syncthreads();

    {   // lin_v: vv = tpv @ Lv  M48 N64 K128; wave -> col-tile wv, 3 row-tiles
        bf16x8 bv[4];
        #pragma unroll
        for (int ks = 0; ks < 4; ++ks)
            bv[ks] = *reinterpret_cast<const bf16x8*>(&LvF[((wv * 4 + ks) * 64 + lane) * 8]);
        int d = wv * 16 + frow;
        int h = d >> 3;
        #pragma unroll
        for (int rt = 0; rt < 3; ++rt) {
            f32x4 acc = {0.f, 0.f, 0.f, 0.f};
            int arow = rt * 16 + frow;
            int swz = (arow & 7) << 3;
            #pragma unroll
            for (int ks = 0; ks < 4; ++ks) {
                bf16x8 a = *reinterpret_cast<const bf16x8*>(&tpv_s[arow * 128 + ((ks * 32 + k8) ^ swz)]);
                acc = __builtin_amdgcn_mfma_f32_16x16x32_bf16(a, bv[ks], acc, 0, 0, 0);
            }
            #pragma unroll
            for (int r = 0; r < 4; ++r) {
                int row = rt * 16 + fgrp * 4 + r;
                int e = row / 3, i = row - e * 3;
                float ex = exb_s[e * 8 + h];
                atomicAdd(&aggv[(size_t)dstb[e] * 192 + d * 3 + i], ex * acc[r]);
            }
        }
    }
}

// ---------------- Kernel 3: normalize + output projections ----------------
__global__ __launch_bounds__(64) void finalize(
    const float* __restrict__ aggs, const float* __restrict__ aggv,
    const float* __restrict__ denom,
    const float* __restrict__ psW, const float* __restrict__ psb,
    const float* __restrict__ pvW,
    float* __restrict__ outs, float* __restrict__ outv)
{
    const int n = blockIdx.x;
    const int tid = threadIdx.x;
    __shared__ float rs[128], rv[192], dn[8];
    if (tid < 8) dn[tid] = 1.f / (denom[n * 8 + tid] + 1e-9f);
    __syncthreads();
    for (int k = tid; k < 128; k += 64) rs[k] = aggs[n * 128 + k] * dn[k >> 4];
    for (int k = tid; k < 192; k += 64) { int d = k / 3; rv[k] = aggv[n * 192 + k] * dn[d >> 3]; }
    __syncthreads();

    {
        float acc = psb[tid];
        #pragma unroll 8
        for (int c = 0; c < 128; ++c) acc = fmaf(rs[c], psW[c * 64 + tid], acc);
        outs[n * 64 + tid] = acc;
    }
    for (int j = tid; j < 96; j += 64) {
        int d = j / 3, i = j - 3 * d;
        float acc = 0.f;
        #pragma unroll 8
        for (int c = 0; c < 64; ++c) acc = fmaf(rv[c * 3 + i], pvW[c * 32 + d], acc);
        outv[n * 96 + j] = acc;
    }
}

extern "C" void kernel_launch(void* const* d_in, const int* in_sizes, int n_in,
                              void* d_out, int out_size, void* d_ws, size_t ws_size,
                              hipStream_t stream) {
    const float* x_s       = (const float*)d_in[0];
    const float* x_v       = (const float*)d_in[1];
    const float* edge_vec  = (const float*)d_in[2];
    const float* edge_scal = (const float*)d_in[3];
    const int*   edge_src  = (const int*)d_in[4];
    const int*   edge_dst  = (const int*)d_in[5];
    const float* Ws_src    = (const float*)d_in[6];
    const float* Ws_dst    = (const float*)d_in[7];
    const float* Wv_src    = (const float*)d_in[8];
    const float* Wv_dst    = (const float*)d_in[9];
    const float* rad_W1    = (const float*)d_in[10];
    const float* rad_b1    = (const float*)d_in[11];
    const float* rad_W2    = (const float*)d_in[12];
    const float* rad_b2    = (const float*)d_in[13];
    const float* lin_s_W   = (const float*)d_in[14];
    const float* lin_s_b   = (const float*)d_in[15];
    const float* lin_v_W   = (const float*)d_in[16];
    const float* alpha_dot = (const float*)d_in[17];
    const float* proj_s_W  = (const float*)d_in[18];
    const float* proj_s_b  = (const float*)d_in[19];
    const float* proj_v_W  = (const float*)d_in[20];

    // workspace layout (19.7 MB total; bf16 node feats halve gather traffic)
    unsigned short* ws16 = (unsigned short*)d_ws;
    unsigned short* ssrc = ws16;                 // N*64 bf16
    unsigned short* sdst = ssrc + 640000;
    unsigned short* vsrc = sdst + 640000;        // N*96 bf16
    unsigned short* vdst = vsrc + 960000;
    float* denom = (float*)(vdst + 960000);      // N*8   (byte off 6.4e6, 16B-aligned)
    float* aggs  = denom + 80000;                // N*128
    float* aggv  = aggs + 1280000;               // N*192
    unsigned short* W1F = (unsigned short*)(aggv + 1920000);  // 8192
    unsigned short* W2F = W1F + 8192;            // 28672
    unsigned short* LsF = W2F + 28672;           // 36864
    unsigned short* LvF = LsF + 36864;           // 8192

    hipMemsetAsync(denom, 0, (size_t)(80000 + 1280000 + 1920000) * sizeof(float), stream);

    prep_weights<<<320, 256, 0, stream>>>(rad_W1, rad_W2, lin_s_W, lin_v_W,
                                          W1F, W2F, LsF, LvF);
    node_xform<<<2048, 256, 0, stream>>>(x_s, x_v, Ws_src, Ws_dst, Wv_src, Wv_dst,
                                         ssrc, sdst, vsrc, vdst);
    edge_kernel<<<N_EDGES / 16, 256, 0, stream>>>(edge_scal, edge_vec, edge_src, edge_dst,
        ssrc, sdst, vsrc, vdst, W1F, W2F, LsF, LvF,
        rad_b1, rad_b2, lin_s_b, alpha_dot, denom, aggs, aggv);

    float* outs = (float*)d_out;
    float* outv = outs + 640000;
    finalize<<<N_NODES, 64, 0, stream>>>(aggs, aggv, denom, proj_s_W, proj_s_b, proj_v_W,
                                         outs, outv);
}

// Round 15
// 460.202 us; speedup vs baseline: 4.3142x; 1.4112x over previous
//
#include <hip/hip_runtime.h>
#include <math.h>

#define N_NODES 10000
#define N_EDGES 160000
// C0=64 C1=32 RBF=64 HID=128 NW=224 HEADS=8 ALPHA_DIM=32 HEAD_S=16 HEAD_V=8
#define SQRT3 1.7320508075688772f
#define INV_SQRT2 0.7071067811865476f

typedef __attribute__((ext_vector_type(8))) short bf16x8;
typedef __attribute__((ext_vector_type(4))) float f32x4;

__device__ __forceinline__ float b2f(unsigned short u) {
    union { unsigned u; float f; } x; x.u = ((unsigned)u) << 16; return x.f;
}
__device__ __forceinline__ unsigned short f2b(float f) {
    union { float f; unsigned u; } x; x.f = f;
    unsigned r = x.u + 0x7FFFu + ((x.u >> 16) & 1u);   // RNE
    return (unsigned short)(r >> 16);
}
__device__ __forceinline__ float sigmoidf_(float x) { return 1.f / (1.f + __expf(-x)); }

// ---------------- Kernel 0: weight prep ----------------
// Re-layout each GEMM weight W[K][N] (f32) into bf16 MFMA B-fragment order:
// F[blk = nt*KS+ks][lane][j] = bf16( W[ks*32 + (lane>>4)*8 + j][nt*16 + (lane&15)] )
__global__ __launch_bounds__(256) void prep_weights(
    const float* __restrict__ W1, const float* __restrict__ W2,
    const float* __restrict__ Ls, const float* __restrict__ Lv,
    unsigned short* __restrict__ F1, unsigned short* __restrict__ F2,
    unsigned short* __restrict__ F3, unsigned short* __restrict__ F4)
{
    int t = blockIdx.x * 256 + threadIdx.x;
    const float* src; unsigned short* dst; int N, KS, rel;
    if      (t < 8192)  { src = W1; dst = F1; N = 128; KS = 2; rel = t; }
    else if (t < 36864) { src = W2; dst = F2; N = 224; KS = 4; rel = t - 8192; }
    else if (t < 73728) { src = Ls; dst = F3; N = 384; KS = 3; rel = t - 36864; }
    else if (t < 81920) { src = Lv; dst = F4; N = 64;  KS = 4; rel = t - 73728; }
    else return;
    int j = rel & 7, lane = (rel >> 3) & 63, blk = rel >> 9;
    int nt = blk / KS, ks = blk - nt * KS;
    int k = ks * 32 + ((lane >> 4) << 3) + j;
    int n = nt * 16 + (lane & 15);
    dst[rel] = f2b(src[k * N + n]);
}

// ---------------- Kernel 1: node transforms (bf16 out) ----------------
__global__ __launch_bounds__(256) void node_xform(
    const float* __restrict__ xs, const float* __restrict__ xv,
    const float* __restrict__ Wss, const float* __restrict__ Wsd,
    const float* __restrict__ Wvs, const float* __restrict__ Wvd,
    unsigned short* __restrict__ ssrc, unsigned short* __restrict__ sdst,
    unsigned short* __restrict__ vsrc, unsigned short* __restrict__ vdst)
{
    const int nth = gridDim.x * blockDim.x;
    const int tid0 = blockIdx.x * blockDim.x + threadIdx.x;

    for (int t = tid0; t < N_NODES * 128; t += nth) {
        int n = t >> 7, r = t & 127, which = r >> 6, d = r & 63;
        const float* W = which ? Wsd : Wss;
        const float* x = xs + n * 64;
        float acc = 0.f;
        #pragma unroll 8
        for (int c = 0; c < 64; ++c) acc = fmaf(x[c], W[c * 64 + d], acc);
        (which ? sdst : ssrc)[n * 64 + d] = f2b(acc);
    }
    for (int t = tid0; t < N_NODES * 192; t += nth) {
        int n = t / 192, r = t % 192, which = r / 96, j = r % 96;
        int d = j / 3, i = j - 3 * d;
        const float* W = which ? Wvd : Wvs;
        const float* x = xv + n * 96;
        float acc = 0.f;
        #pragma unroll 8
        for (int c = 0; c < 32; ++c) acc = fmaf(x[c * 3 + i], W[c * 32 + d], acc);
        (which ? vdst : vsrc)[n * 96 + j] = f2b(acc);
    }
}

// ---------------- Kernel 2: fused per-edge pipeline, MFMA GEMMs ----------------
// 16 edges/block, 4 waves, 5 blocks/CU (LDS overlay: es/h region reused as tps).
__global__ __launch_bounds__(256, 5) void edge_kernel(
    const float* __restrict__ edge_scalars, const float* __restrict__ edge_vec,
    const int* __restrict__ edge_src, const int* __restrict__ edge_dst,
    const unsigned short* __restrict__ ssrc, const unsigned short* __restrict__ sdst,
    const unsigned short* __restrict__ vsrc, const unsigned short* __restrict__ vdst,
    const unsigned short* __restrict__ W1F, const unsigned short* __restrict__ W2F,
    const unsigned short* __restrict__ LsF, const unsigned short* __restrict__ LvF,
    const float* __restrict__ rad_b1, const float* __restrict__ rad_b2,
    const float* __restrict__ lin_s_b, const float* __restrict__ alpha_dot,
    float* __restrict__ denom, float* __restrict__ aggs, float* __restrict__ aggv)
{
    // R1 overlay: phases 1-2: es_s[1024] at [0), h_s[2048] at [1024).
    //             phase 3+:  tps_s[2048] at [0)  (es dead after rad1, h dead after rad2)
    __shared__ unsigned short R1[3072];
    __shared__ unsigned short tpv_s[6144];   // 48 rows x 128, swizzled
    __shared__ unsigned short ms_s[1024];
    __shared__ unsigned short mv_s[1536];
    __shared__ unsigned short w_s[3584];     // 16 x 224
    __shared__ float exb_s[128];
    __shared__ float unitb[16][3];
    __shared__ int dstb[16];

    unsigned short* es_s  = R1;          // 16 x 64, swizzled
    unsigned short* h_s   = R1 + 1024;   // 16 x 128, swizzled
    unsigned short* tps_s = R1;          // 16 x 128 (cols 0..95 used), swizzled

    const int tid = threadIdx.x;
    const int e0 = blockIdx.x * 16;
    const int lane = tid & 63;
    const int wv = tid >> 6;
    const int frow = lane & 15;   // A-row / D-col within tile
    const int fgrp = lane >> 4;   // k-group / D-row group
    const int k8 = fgrp << 3;

    if (tid < 16) {
        dstb[tid] = edge_dst[e0 + tid];
        float x = edge_vec[(e0 + tid) * 3 + 0];
        float y = edge_vec[(e0 + tid) * 3 + 1];
        float z = edge_vec[(e0 + tid) * 3 + 2];
        float rn = 1.f / (sqrtf(x * x + y * y + z * z) + 1e-9f);
        unitb[tid][0] = x * rn; unitb[tid][1] = y * rn; unitb[tid][2] = z * rn;
    }
    #pragma unroll
    for (int k = 0; k < 4; ++k) {
        int idx = tid + k * 256, e = idx >> 6, c = idx & 63;
        es_s[e * 64 + (c ^ ((e & 7) << 3))] = f2b(edge_scalars[(size_t)(e0 + e) * 64 + c]);
    }
    __syncthreads();

    // ---- gathers (wave-uniform edge rows -> scalar src/dst, coalesced loads);
    //      overlap with rad1; consumed after the rad2 barrier ----
    #pragma unroll
    for (int k = 0; k < 4; ++k) {
        int e = wv + 4 * k;
        int se = edge_src[e0 + e], de = edge_dst[e0 + e];
        ms_s[e * 64 + lane] = f2b(b2f(ssrc[se * 64 + lane]) + b2f(sdst[de * 64 + lane]));
        mv_s[e * 96 + lane] = f2b(b2f(vsrc[se * 96 + lane]) + b2f(vdst[de * 96 + lane]));
        if (lane < 32)
            mv_s[e * 96 + 64 + lane] = f2b(b2f(vsrc[se * 96 + 64 + lane]) + b2f(vdst[de * 96 + 64 + lane]));
    }
    {   // rad1: h = silu(es @ W1 + b1)   M16 N128 K64; wave -> 2 col-tiles
        const int swz = (frow & 7) << 3;
        bf16x8 a0 = *reinterpret_cast<const bf16x8*>(&es_s[frow * 64 + (k8 ^ swz)]);
        bf16x8 a1 = *reinterpret_cast<const bf16x8*>(&es_s[frow * 64 + ((32 + k8) ^ swz)]);
        #pragma unroll
        for (int t = 0; t < 2; ++t) {
            int nt = wv * 2 + t;
            f32x4 acc = {0.f, 0.f, 0.f, 0.f};
            acc = __builtin_amdgcn_mfma_f32_16x16x32_bf16(a0,
                  *reinterpret_cast<const bf16x8*>(&W1F[((nt * 2 + 0) * 64 + lane) * 8]), acc, 0, 0, 0);
            acc = __builtin_amdgcn_mfma_f32_16x16x32_bf16(a1,
                  *reinterpret_cast<const bf16x8*>(&W1F[((nt * 2 + 1) * 64 + lane) * 8]), acc, 0, 0, 0);
            int col = nt * 16 + frow;
            float bias = rad_b1[col];
            #pragma unroll
            for (int r = 0; r < 4; ++r) {
                int row = fgrp * 4 + r;
                float x = acc[r] + bias;
                h_s[row * 128 + (col ^ ((row & 7) << 3))] = f2b(x * sigmoidf_(x));
            }
        }
    }
    __syncthreads();

    {   // rad2: w = h @ W2 + b2   M16 N224 K128; 14 tiles over 4 waves
        const int swz = (frow & 7) << 3;
        bf16x8 ah[4];
        #pragma unroll
        for (int ks = 0; ks < 4; ++ks)
            ah[ks] = *reinterpret_cast<const bf16x8*>(&h_s[frow * 128 + ((ks * 32 + k8) ^ swz)]);
        for (int nt = wv; nt < 14; nt += 4) {
            f32x4 acc = {0.f, 0.f, 0.f, 0.f};
            #pragma unroll
            for (int ks = 0; ks < 4; ++ks)
                acc = __builtin_amdgcn_mfma_f32_16x16x32_bf16(ah[ks],
                      *reinterpret_cast<const bf16x8*>(&W2F[((nt * 4 + ks) * 64 + lane) * 8]), acc, 0, 0, 0);
            int col = nt * 16 + frow;
            float bias = rad_b2[col];
            #pragma unroll
            for (int r = 0; r < 4; ++r) {
                int row = fgrp * 4 + r;
                w_s[row * 224 + col] = f2b(acc[r] + bias);
            }
        }
    }
    __syncthreads();

    // ---- tp assembly (elementwise f32, bf16 in/out); tps overwrites es/h region ----
    // w layout: A[0:64] B[64:128] C[128:160] D[160:192] E[192:224]
    #pragma unroll
    for (int k = 0; k < 4; ++k) {   // tps cols 0..63: wA*ms
        int idx = tid + k * 256, e = idx >> 6, j = idx & 63;
        float v = b2f(w_s[e * 224 + j]) * b2f(ms_s[e * 64 + j]);
        tps_s[e * 128 + (j ^ ((e & 7) << 3))] = f2b(v);
    }
    #pragma unroll
    for (int k = 0; k < 2; ++k) {   // tps cols 64..95: wD*(mv.unit)
        int idx = tid + k * 256, e = idx >> 5, d = idx & 31;
        float dot = b2f(mv_s[e * 96 + d * 3 + 0]) * unitb[e][0]
                  + b2f(mv_s[e * 96 + d * 3 + 1]) * unitb[e][1]
                  + b2f(mv_s[e * 96 + d * 3 + 2]) * unitb[e][2];
        float v = b2f(w_s[e * 224 + 160 + d]) * dot;
        int j = 64 + d;
        tps_s[e * 128 + (j ^ ((e & 7) << 3))] = f2b(v);
    }
    // tpv rows=(e,i) 48 x 128, three branch-free passes
    #pragma unroll
    for (int k = 0; k < 12; ++k) {  // cols 0..63: wB*ms*sqrt3*unit_i
        int idx = tid + k * 256;
        int row = idx >> 6, c = idx & 63;
        int e = row / 3, i = row - e * 3;
        float v = b2f(w_s[e * 224 + 64 + c]) * b2f(ms_s[e * 64 + c]) * SQRT3 * unitb[e][i];
        tpv_s[row * 128 + (c ^ ((row & 7) << 3))] = f2b(v);
    }
    #pragma unroll
    for (int k = 0; k < 6; ++k) {   // cols 64..95: wC*mv_i
        int idx = tid + k * 256;
        int row = idx >> 5, d = idx & 31;
        int e = row / 3, i = row - e * 3;
        float v = b2f(w_s[e * 224 + 128 + d]) * b2f(mv_s[e * 96 + d * 3 + i]);
        int c = 64 + d;
        tpv_s[row * 128 + (c ^ ((row & 7) << 3))] = f2b(v);
    }
    #pragma unroll
    for (int k = 0; k < 6; ++k) {   // cols 96..127: wE*cross(mv,unit)_i*sqrt3/sqrt2
        int idx = tid + k * 256;
        int row = idx >> 5, d = idx & 31;
        int e = row / 3, i = row - e * 3;
        float m0 = b2f(mv_s[e * 96 + d * 3 + 0]);
        float m1 = b2f(mv_s[e * 96 + d * 3 + 1]);
        float m2 = b2f(mv_s[e * 96 + d * 3 + 2]);
        float cr = (i == 0) ? (m1 * unitb[e][2] - m2 * unitb[e][1])
                 : (i == 1) ? (m2 * unitb[e][0] - m0 * unitb[e][2])
                            : (m0 * unitb[e][1] - m1 * unitb[e][0]);
        float v = b2f(w_s[e * 224 + 192 + d]) * cr * (SQRT3 * INV_SQRT2);
        int c = 96 + d;
        tpv_s[row * 128 + (c ^ ((row & 7) << 3))] = f2b(v);
    }
    __syncthreads();

    {   // lin_s: f_s = tps @ Ls + b  M16 N384 K96; wave -> 6 tiles = heads 2w,2w+1
        const int swz = (frow & 7) << 3;
        bf16x8 at[3];
        #pragma unroll
        for (int ks = 0; ks < 3; ++ks)
            at[ks] = *reinterpret_cast<const bf16x8*>(&tps_s[frow * 128 + ((ks * 32 + k8) ^ swz)]);
        f32x4 acc[6];
        #pragma unroll
        for (int t = 0; t < 6; ++t) {
            int nt = wv * 6 + t;
            f32x4 a = {0.f, 0.f, 0.f, 0.f};
            #pragma unroll
            for (int ks = 0; ks < 3; ++ks)
                a = __builtin_amdgcn_mfma_f32_16x16x32_bf16(at[ks],
                    *reinterpret_cast<const bf16x8*>(&LsF[((nt * 3 + ks) * 64 + lane) * 8]), a, 0, 0, 0);
            float bias = lin_s_b[nt * 16 + frow];
            a[0] += bias; a[1] += bias; a[2] += bias; a[3] += bias;
            acc[t] = a;
        }
        #pragma unroll
        for (int hh = 0; hh < 2; ++hh) {
            int h = wv * 2 + hh, t0 = hh * 3;
            float ad0 = alpha_dot[h * 32 + frow];
            float ad1 = alpha_dot[h * 32 + 16 + frow];
            float part[4];
            #pragma unroll
            for (int r = 0; r < 4; ++r) {
                float x0 = acc[t0][r], x1 = acc[t0 + 1][r];
                float s0 = 0.6f * x0 + 0.4f * x0 * (2.f * sigmoidf_(x0) - 1.f);
                float s1 = 0.6f * x1 + 0.4f * x1 * (2.f * sigmoidf_(x1) - 1.f);
                part[r] = s0 * ad0 + s1 * ad1;
            }
            #pragma unroll
            for (int off = 1; off < 16; off <<= 1) {
                #pragma unroll
                for (int r = 0; r < 4; ++r) part[r] += __shfl_xor(part[r], off, 64);
            }
            #pragma unroll
            for (int r = 0; r < 4; ++r) {
                float ex = __expf(part[r]);   // no max-subtraction: normalized later
                int e = fgrp * 4 + r;
                int dst = dstb[e];
                if (frow == 0) { atomicAdd(&denom[dst * 8 + h], ex); exb_s[e * 8 + h] = ex; }
                atomicAdd(&aggs[(size_t)dst * 128 + h * 16 + frow], ex * acc[t0 + 2][r]);
            }
        }
    }
    __syncthreads();

    {   // lin_v: vv = tpv @ Lv  M48 N64 K128; wave -> col-tile wv, 3 row-tiles
        // aggv layout: [n][i*64+d] -> each 16-lane atomic group is 64B-contiguous
        bf16x8 bv[4];
        #pragma unroll
        for (int ks = 0; ks < 4; ++ks)
            bv[ks] = *reinterpret_cast<const bf16x8*>(&LvF[((wv * 4 + ks) * 64 + lane) * 8]);
        int d = wv * 16 + frow;
        int h = d >> 3;
        #pragma unroll
        for (int rt = 0; rt < 3; ++rt) {
            f32x4 acc = {0.f, 0.f, 0.f, 0.f};
            int arow = rt * 16 + frow;
            int swz = (arow & 7) << 3;
            #pragma unroll
            for (int ks = 0; ks < 4; ++ks) {
                bf16x8 a = *reinterpret_cast<const bf16x8*>(&tpv_s[arow * 128 + ((ks * 32 + k8) ^ swz)]);
                acc = __builtin_amdgcn_mfma_f32_16x16x32_bf16(a, bv[ks], acc, 0, 0, 0);
            }
            #pragma unroll
            for (int r = 0; r < 4; ++r) {
                int row = rt * 16 + fgrp * 4 + r;
                int e = row / 3, i = row - e * 3;
                float ex = exb_s[e * 8 + h];
                atomicAdd(&aggv[(size_t)dstb[e] * 192 + i * 64 + d], ex * acc[r]);
            }
        }
    }
}

// ---------------- Kernel 3: normalize + output projections (4 nodes/block) ----------------
__global__ __launch_bounds__(256) void finalize(
    const float* __restrict__ aggs, const float* __restrict__ aggv,
    const float* __restrict__ denom,
    const float* __restrict__ psW, const float* __restrict__ psb,
    const float* __restrict__ pvW,
    float* __restrict__ outs, float* __restrict__ outv)
{
    const int g = threadIdx.x >> 6;
    const int n = blockIdx.x * 4 + g;
    const int tid = threadIdx.x & 63;
    __shared__ float rs[4][128], rv[4][192], dn[4][8];
    if (tid < 8) dn[g][tid] = 1.f / (denom[n * 8 + tid] + 1e-9f);
    __syncthreads();
    for (int k = tid; k < 128; k += 64) rs[g][k] = aggs[n * 128 + k] * dn[g][k >> 4];
    // aggv layout [n][i*64+d]: head = d>>3 = ((k&63)>>3)
    for (int k = tid; k < 192; k += 64) rv[g][k] = aggv[n * 192 + k] * dn[g][(k & 63) >> 3];
    __syncthreads();

    {
        float acc = psb[tid];
        #pragma unroll 8
        for (int c = 0; c < 128; ++c) acc = fmaf(rs[g][c], psW[c * 64 + tid], acc);
        outs[n * 64 + tid] = acc;
    }
    for (int j = tid; j < 96; j += 64) {
        int d = j / 3, i = j - 3 * d;
        float acc = 0.f;
        #pragma unroll 8
        for (int c = 0; c < 64; ++c) acc = fmaf(rv[g][i * 64 + c], pvW[c * 32 + d], acc);
        outv[n * 96 + j] = acc;
    }
}

extern "C" void kernel_launch(void* const* d_in, const int* in_sizes, int n_in,
                              void* d_out, int out_size, void* d_ws, size_t ws_size,
                              hipStream_t stream) {
    const float* x_s       = (const float*)d_in[0];
    const float* x_v       = (const float*)d_in[1];
    const float* edge_vec  = (const float*)d_in[2];
    const float* edge_scal = (const float*)d_in[3];
    const int*   edge_src  = (const int*)d_in[4];
    const int*   edge_dst  = (const int*)d_in[5];
    const float* Ws_src    = (const float*)d_in[6];
    const float* Ws_dst    = (const float*)d_in[7];
    const float* Wv_src    = (const float*)d_in[8];
    const float* Wv_dst    = (const float*)d_in[9];
    const float* rad_W1    = (const float*)d_in[10];
    const float* rad_b1    = (const float*)d_in[11];
    const float* rad_W2    = (const float*)d_in[12];
    const float* rad_b2    = (const float*)d_in[13];
    const float* lin_s_W   = (const float*)d_in[14];
    const float* lin_s_b   = (const float*)d_in[15];
    const float* lin_v_W   = (const float*)d_in[16];
    const float* alpha_dot = (const float*)d_in[17];
    const float* proj_s_W  = (const float*)d_in[18];
    const float* proj_s_b  = (const float*)d_in[19];
    const float* proj_v_W  = (const float*)d_in[20];

    unsigned short* ws16 = (unsigned short*)d_ws;
    unsigned short* ssrc = ws16;                 // N*64 bf16
    unsigned short* sdst = ssrc + 640000;
    unsigned short* vsrc = sdst + 640000;        // N*96 bf16
    unsigned short* vdst = vsrc + 960000;
    float* denom = (float*)(vdst + 960000);      // N*8
    float* aggs  = denom + 80000;                // N*128
    float* aggv  = aggs + 1280000;               // N*192  ([n][i*64+d])
    unsigned short* W1F = (unsigned short*)(aggv + 1920000);  // 8192
    unsigned short* W2F = W1F + 8192;            // 28672
    unsigned short* LsF = W2F + 28672;           // 36864
    unsigned short* LvF = LsF + 36864;           // 8192

    hipMemsetAsync(denom, 0, (size_t)(80000 + 1280000 + 1920000) * sizeof(float), stream);

    prep_weights<<<320, 256, 0, stream>>>(rad_W1, rad_W2, lin_s_W, lin_v_W,
                                          W1F, W2F, LsF, LvF);
    node_xform<<<2048, 256, 0, stream>>>(x_s, x_v, Ws_src, Ws_dst, Wv_src, Wv_dst,
                                         ssrc, sdst, vsrc, vdst);
    edge_kernel<<<N_EDGES / 16, 256, 0, stream>>>(edge_scal, edge_vec, edge_src, edge_dst,
        ssrc, sdst, vsrc, vdst, W1F, W2F, LsF, LvF,
        rad_b1, rad_b2, lin_s_b, alpha_dot, denom, aggs, aggv);

    float* outs = (float*)d_out;
    float* outv = outs + 640000;
    finalize<<<2500, 256, 0, stream>>>(aggs, aggv, denom, proj_s_W, proj_s_b, proj_v_W,
                                       outs, outv);
}